// Round 1
// baseline (253.633 us; speedup 1.0000x reference)
//
#include <hip/hip_runtime.h>

#define BSZ 16
#define CIN 32
#define NIN 8
#define HH 20
#define WW 20
#define CON 32
#define NON 8
#define OCN 256   // CON*NON
#define KK  72    // NIN*3*3
#define ITERS 3

__global__ __launch_bounds__(256, 3)
void caps_fused_kernel(const float* __restrict__ x,
                       const float* __restrict__ Wt,
                       const float* __restrict__ bias,
                       float* __restrict__ out) {
    __shared__ __align__(16) float xp[CIN][KK];       // 9216 B
    __shared__ __align__(16) float votes[CIN][OCN];   // 32768 B
    __shared__ float logits[CIN][CON + 1];            // 4224 B (pad: col access conflict-free)
    __shared__ float route[CIN][CON + 1];             // 4224 B
    __shared__ float act[OCN];                        // 1024 B

    const int t   = threadIdx.x;
    const int bi  = blockIdx.x;
    const int b   = bi / (HH * WW);
    const int rem = bi % (HH * WW);
    const int h   = rem / WW;
    const int w   = rem % WW;

    // ---- stage zero-padded x patch: xp[ci][ni*9 + kh*3 + kw] ----
    for (int e = t; e < CIN * KK; e += 256) {
        int ci = e / KK;
        int k  = e % KK;
        int ni = k / 9;
        int r  = k % 9;
        int hh = h + r / 3 - 1;
        int ww = w + r % 3 - 1;
        float v = 0.f;
        if (hh >= 0 && hh < HH && ww >= 0 && ww < WW)
            v = x[(((b * CIN + ci) * NIN + ni) * HH + hh) * WW + ww];
        xp[ci][k] = v;
    }
    // ---- init logits ----
    for (int e = t; e < CIN * CON; e += 256) {
        int ci = e >> 5, co = e & 31;
        logits[ci][co] = 0.f;
    }

    // ---- per-thread conv weights (oc = t), 18 x float4, 288B-aligned rows ----
    const int oc = t;
    float4 wreg[18];
    const float4* wp = (const float4*)(Wt + oc * KK);
#pragma unroll
    for (int j = 0; j < 18; ++j) wreg[j] = wp[j];
    const float bsv = bias[oc];

    __syncthreads();

    // ---- conv: votes[ci][oc] = dot(W[oc,:], xp[ci,:]) over K=72 ----
    for (int ci = 0; ci < CIN; ++ci) {
        float acc = 0.f;
        const float4* xv4 = (const float4*)xp[ci];
#pragma unroll
        for (int j = 0; j < 18; ++j) {
            float4 xv = xv4[j];
            acc = fmaf(wreg[j].x, xv.x, acc);
            acc = fmaf(wreg[j].y, xv.y, acc);
            acc = fmaf(wreg[j].z, xv.z, acc);
            acc = fmaf(wreg[j].w, xv.w, acc);
        }
        votes[ci][oc] = acc;
    }
    __syncthreads();

    // ---- dynamic routing ----
    const int co_t = t >> 3;   // this thread's co for preact/squash
    float activation = 0.f;

    for (int it = 0; it < ITERS; ++it) {
        // softmax over co per ci-row; threads 0..31 each own a row.
        if (t < CIN) {
            const int ci = t;
            float m = -1e30f;
#pragma unroll
            for (int c = 0; c < CON; ++c) m = fmaxf(m, logits[ci][c]);
            float s = 0.f;
#pragma unroll
            for (int c = 0; c < CON; ++c) {
                float e = __expf(logits[ci][c] - m);
                route[ci][c] = e;
                s += e;
            }
            float inv = 1.f / s;
#pragma unroll
            for (int c = 0; c < CON; ++c) route[ci][c] *= inv;
        }
        __syncthreads();

        // preact[oc] = bias + sum_ci route[ci][co] * votes[ci][oc]
        float p = bsv;
#pragma unroll 4
        for (int ci = 0; ci < CIN; ++ci)
            p = fmaf(route[ci][co_t], votes[ci][oc], p);

        // squash over no (8 consecutive lanes share a co)
        float n2 = p * p;
        n2 += __shfl_xor(n2, 1);
        n2 += __shfl_xor(n2, 2);
        n2 += __shfl_xor(n2, 4);
        activation = p * (n2 / ((1.f + n2) * sqrtf(n2 + 1e-9f)));
        act[oc] = activation;
        __syncthreads();

        // distances: logits[ci][co] += sum_no votes[ci][co*8+no] * act[co*8+no]
        if (it < ITERS - 1) {
#pragma unroll
            for (int j = 0; j < 4; ++j) {
                int e  = t + 256 * j;
                int ci = e >> 5, co = e & 31;
                float d = 0.f;
#pragma unroll
                for (int no = 0; no < NON; ++no)
                    d = fmaf(votes[ci][co * 8 + no], act[co * 8 + no], d);
                logits[ci][co] += d;
            }
            __syncthreads();
        }
    }

    // ---- write out: out[b][co][no][h][w], oc = co*8+no = t ----
    out[(b * OCN + t) * (HH * WW) + h * WW + w] = activation;
}

extern "C" void kernel_launch(void* const* d_in, const int* in_sizes, int n_in,
                              void* d_out, int out_size, void* d_ws, size_t ws_size,
                              hipStream_t stream) {
    const float* x    = (const float*)d_in[0];
    const float* Wt   = (const float*)d_in[1];
    const float* bias = (const float*)d_in[2];
    float* out        = (float*)d_out;

    dim3 grid(BSZ * HH * WW);
    dim3 block(256);
    caps_fused_kernel<<<grid, block, 0, stream>>>(x, Wt, bias, out);
}

// Round 2
// 137.644 us; speedup vs baseline: 1.8427x; 1.8427x over previous
//
#include <hip/hip_runtime.h>

#define HH 20
#define WW 20
#define ITERS 3

typedef __bf16  bf16x8 __attribute__((ext_vector_type(8)));
typedef float   f32x4  __attribute__((ext_vector_type(4)));

// LDS:
//  region0 (union): A_hi[32][104] + A_lo[32][104] bf16 (13312 B)
//                   vbuf[32][128] float (16384 B)          -> 16384
//  logits[32][37] f32 (4736) + route[32][37] f32 (4736)
//  total 25856 B -> LDS allows 6 blocks/CU; VGPR/launch_bounds caps at 4.
__global__ __launch_bounds__(256, 4)
void caps_mfma_kernel(const float* __restrict__ x,
                      const float* __restrict__ Wt,
                      const float* __restrict__ bias,
                      float* __restrict__ out) {
    __shared__ __align__(16) unsigned char u_region[16384];
    __shared__ float logits[32][37];
    __shared__ float route[32][37];

    __bf16* A_hi = (__bf16*)u_region;          // [32][104]
    __bf16* A_lo = A_hi + 32 * 104;            // [32][104]
    float (*vbuf)[128] = (float (*)[128])u_region;

    const int t  = threadIdx.x;
    const int l  = t & 63;
    const int wv = t >> 6;
    const int lr = l & 15;     // M-row / N-col within 16x16 tile
    const int lg = l >> 4;     // k-group (8 elems each)

    const int bi  = blockIdx.x;
    const int b   = bi / (HH * WW);
    const int rem = bi % (HH * WW);
    const int h   = rem / WW;
    const int w   = rem % WW;

    // ---- stage x patch as split-bf16: A[ci][k], k = ni*9+kh*3+kw, pad k>=72 with 0
    for (int e = t; e < 32 * 104; e += 256) {
        int ci = e / 104, k = e % 104;
        float v = 0.f;
        if (k < 72) {
            int ni = k / 9, r = k % 9;
            int hh = h + r / 3 - 1, ww = w + r % 3 - 1;
            if (hh >= 0 && hh < HH && ww >= 0 && ww < WW)
                v = x[(((b * 32 + ci) * 8 + ni) * HH + hh) * WW + ww];
        }
        __bf16 hi = (__bf16)v;
        __bf16 lo = (__bf16)(v - (float)hi);
        A_hi[ci * 104 + k] = hi;
        A_lo[ci * 104 + k] = lo;
    }
    for (int e = t; e < 32 * 37; e += 256) ((float*)logits)[e] = 0.f;
    __syncthreads();

    // ---- conv via MFMA: votes = Ah*Bh + Ah*Bl + Al*Bh   (M=32, N=256, K=72->96)
    f32x4 acc[4][2];
#pragma unroll
    for (int i = 0; i < 4; ++i)
#pragma unroll
        for (int m = 0; m < 2; ++m) acc[i][m] = (f32x4){0.f, 0.f, 0.f, 0.f};

#pragma unroll
    for (int kst = 0; kst < 3; ++kst) {
        const int kb = kst * 32 + lg * 8;
        bf16x8 a_h0 = *(const bf16x8*)&A_hi[(0  + lr) * 104 + kb];
        bf16x8 a_h1 = *(const bf16x8*)&A_hi[(16 + lr) * 104 + kb];
        bf16x8 a_l0 = *(const bf16x8*)&A_lo[(0  + lr) * 104 + kb];
        bf16x8 a_l1 = *(const bf16x8*)&A_lo[(16 + lr) * 104 + kb];
#pragma unroll
        for (int i = 0; i < 4; ++i) {
            const int nt = wv * 4 + i;
            const int oc = nt * 16 + lr;
            bf16x8 bh = {};
            bf16x8 bl = {};
            if (kb < 72) {                       // k-pad region contributes 0
                const float* wp = Wt + oc * 72 + kb;
                float4 w0 = *(const float4*)wp;
                float4 w1 = *(const float4*)(wp + 4);
                float wr[8] = {w0.x, w0.y, w0.z, w0.w, w1.x, w1.y, w1.z, w1.w};
#pragma unroll
                for (int j = 0; j < 8; ++j) {
                    __bf16 hb = (__bf16)wr[j];
                    bh[j] = hb;
                    bl[j] = (__bf16)(wr[j] - (float)hb);
                }
            }
            acc[i][0] = __builtin_amdgcn_mfma_f32_16x16x32_bf16(a_h0, bh, acc[i][0], 0, 0, 0);
            acc[i][1] = __builtin_amdgcn_mfma_f32_16x16x32_bf16(a_h1, bh, acc[i][1], 0, 0, 0);
            acc[i][0] = __builtin_amdgcn_mfma_f32_16x16x32_bf16(a_l0, bh, acc[i][0], 0, 0, 0);
            acc[i][1] = __builtin_amdgcn_mfma_f32_16x16x32_bf16(a_l1, bh, acc[i][1], 0, 0, 0);
            acc[i][0] = __builtin_amdgcn_mfma_f32_16x16x32_bf16(a_h0, bl, acc[i][0], 0, 0, 0);
            acc[i][1] = __builtin_amdgcn_mfma_f32_16x16x32_bf16(a_h1, bl, acc[i][1], 0, 0, 0);
        }
    }

    // ---- transpose D-frags -> per-thread votes column vcol[ci] (oc = t), two passes
    float vcol[32];
#pragma unroll
    for (int p = 0; p < 2; ++p) {
        __syncthreads();                       // A region dead / prev pass reads done
        if ((wv >> 1) == p) {
#pragma unroll
            for (int i = 0; i < 4; ++i) {
                const int colbase = (wv * 4 + i) * 16 + lr - p * 128;
#pragma unroll
                for (int m = 0; m < 2; ++m)
#pragma unroll
                    for (int r = 0; r < 4; ++r)
                        vbuf[m * 16 + lg * 4 + r][colbase] = acc[i][m][r];
            }
        }
        __syncthreads();
        if ((t >> 7) == p) {
            const int cc = t & 127;
#pragma unroll
            for (int ci = 0; ci < 32; ++ci) vcol[ci] = vbuf[ci][cc];
        }
    }

    // ---- dynamic routing (register-centric). Thread t owns oc=t; co=t>>3, no=t&7.
    const int co = t >> 3;
    const int no = t & 7;
    const float bsv = bias[t];
    float act = 0.f;

    for (int it = 0; it < ITERS; ++it) {
        // softmax over co for each ci: thread handles (ci = t>>3, cols c0+8j)
        {
            const int ci = t >> 3;
            const int c0 = t & 7;
            float l0 = logits[ci][c0],      l1 = logits[ci][c0 + 8];
            float l2 = logits[ci][c0 + 16], l3 = logits[ci][c0 + 24];
            float m = fmaxf(fmaxf(l0, l1), fmaxf(l2, l3));
            m = fmaxf(m, __shfl_xor(m, 1));
            m = fmaxf(m, __shfl_xor(m, 2));
            m = fmaxf(m, __shfl_xor(m, 4));
            float e0 = __expf(l0 - m), e1 = __expf(l1 - m);
            float e2 = __expf(l2 - m), e3 = __expf(l3 - m);
            float s = e0 + e1 + e2 + e3;
            s += __shfl_xor(s, 1);
            s += __shfl_xor(s, 2);
            s += __shfl_xor(s, 4);
            float inv = 1.f / s;
            route[ci][c0]      = e0 * inv;
            route[ci][c0 + 8]  = e1 * inv;
            route[ci][c0 + 16] = e2 * inv;
            route[ci][c0 + 24] = e3 * inv;
        }
        __syncthreads();

        // preact for oc=t
        float p = bsv;
#pragma unroll
        for (int ci = 0; ci < 32; ++ci) p = fmaf(route[ci][co], vcol[ci], p);

        // squash over no-group (8 lanes)
        float n2 = p * p;
        n2 += __shfl_xor(n2, 1);
        n2 += __shfl_xor(n2, 2);
        n2 += __shfl_xor(n2, 4);
        act = p * (n2 / ((1.f + n2) * sqrtf(n2 + 1e-9f)));

        // distances -> logits update (skip on last iter)
        if (it < ITERS - 1) {
#pragma unroll
            for (int ci = 0; ci < 32; ++ci) {
                float pd = vcol[ci] * act;
                pd += __shfl_xor(pd, 1);
                pd += __shfl_xor(pd, 2);
                pd += __shfl_xor(pd, 4);          // all 8 lanes: d[ci][co]
                if ((ci >> 2) == no)              // unique (ci,co) writer
                    logits[ci][co] += pd;
            }
        }
        __syncthreads();
    }

    // ---- out[b][co][no][h][w]
    out[(b * 256 + t) * (HH * WW) + h * WW + w] = act;
}

extern "C" void kernel_launch(void* const* d_in, const int* in_sizes, int n_in,
                              void* d_out, int out_size, void* d_ws, size_t ws_size,
                              hipStream_t stream) {
    const float* x    = (const float*)d_in[0];
    const float* Wt   = (const float*)d_in[1];
    const float* bias = (const float*)d_in[2];
    float* out        = (float*)d_out;

    caps_mfma_kernel<<<dim3(16 * HH * WW), dim3(256), 0, stream>>>(x, Wt, bias, out);
}

// Round 3
// 109.733 us; speedup vs baseline: 2.3114x; 1.2543x over previous
//
#include <hip/hip_runtime.h>

#define HH 20
#define WW 20
#define ITERS 3

typedef __bf16  bf16x8 __attribute__((ext_vector_type(8)));
typedef float   f32x4  __attribute__((ext_vector_type(4)));
typedef float   f32x4u __attribute__((ext_vector_type(4), aligned(4)));

// ---------------- prologue: prepack W -> split bf16, K padded 72->96 ----------------
// ws layout: Bh[256][96] bf16, then Bl[256][96] bf16  (98304 B total)
__global__ void prepack_w_kernel(const float* __restrict__ Wt, __bf16* __restrict__ bp) {
    int idx = blockIdx.x * 256 + threadIdx.x;   // 24576 = 256 oc * 96 k
    int oc = idx / 96, k = idx % 96;
    float v = (k < 72) ? Wt[oc * 72 + k] : 0.f;
    __bf16 hi = (__bf16)v;
    bp[idx]           = hi;                      // Bh
    bp[24576 + idx]   = (__bf16)(v - (float)hi); // Bl
}

// ---------------- main fused kernel ----------------
// LDS: u_region 16384 B  = A_hi[32][104] + A_lo[32][104] bf16 (13312) / vbuf[32][128] f32
//      logits[32][37] f32 (4736), route_T[32][36] f32 (4608)  -> total 25728 B (6 blocks/CU)
__global__ __launch_bounds__(256, 6)
void caps_mfma2_kernel(const float* __restrict__ x,
                       const __bf16* __restrict__ bp,
                       const float* __restrict__ bias,
                       float* __restrict__ out) {
    __shared__ __align__(16) unsigned char u_region[16384];
    __shared__ float logits[32][37];
    __shared__ float route_T[32][36];   // [co][ci]

    __bf16* A_hi = (__bf16*)u_region;            // [32][104]
    __bf16* A_lo = A_hi + 32 * 104;
    float (*vbuf)[128] = (float (*)[128])u_region;

    const int t  = threadIdx.x;
    const int l  = t & 63;
    const int wv = t >> 6;
    const int lr = l & 15;
    const int lg = l >> 4;

    const int bi  = blockIdx.x;
    const int b   = bi / (HH * WW);
    const int rem = bi % (HH * WW);
    const int h   = rem / WW;
    const int w   = rem % WW;

    // ---- zero k-pad region of A (k in [72,104)) as b32 stores ----
#pragma unroll
    for (int e = t; e < 1024; e += 256) {         // 32 ci * 16 u32
        int ci = e >> 4, j = e & 15;
        ((unsigned int*)&A_hi[ci * 104 + 72])[j] = 0u;
        ((unsigned int*)&A_lo[ci * 104 + 72])[j] = 0u;
    }

    // ---- stage x patch, split bf16. 768 segments = 32ci * 8ni * 3hr ----
    const int wlo    = min(max(w - 1, 0), WW - 4);
    const int dshift = (w - 1) - wlo;             // 0 normally; 1 at w=0; 1/2 at w=18/19... (w-1-wlo)
#pragma unroll
    for (int s = t; s < 768; s += 256) {
        int ci = s / 24;
        int r  = s % 24;
        int ni = r / 3, hr = r % 3;
        int hh = h - 1 + hr;
        bool hok = (hh >= 0) && (hh < HH);
        const float* rowp = x + ((((b * 32 + ci) * 8 + ni) * HH + (hok ? hh : 0)) * WW) + wlo;
        f32x4u f4 = *(const f32x4u*)rowp;
        int kbase = ni * 9 + hr * 3;
#pragma unroll
        for (int kw = 0; kw < 3; ++kw) {
            int ww = w - 1 + kw;
            int j  = kw + dshift;                  // in [0,3] whenever ww valid
            float v = 0.f;
            if (hok && ww >= 0 && ww < WW)
                v = (j == 0) ? f4.x : (j == 1) ? f4.y : (j == 2) ? f4.z : f4.w;
            __bf16 hi = (__bf16)v;
            A_hi[ci * 104 + kbase + kw] = hi;
            A_lo[ci * 104 + kbase + kw] = (__bf16)(v - (float)hi);
        }
    }
    __syncthreads();

    // ---- conv via MFMA: votes = Ah*Bh + Al*Bh + Ah*Bl  (M=32,N=256,K=96) ----
    const __bf16* Bh = bp;
    const __bf16* Bl = bp + 24576;
    f32x4 acc[4][2];
#pragma unroll
    for (int i = 0; i < 4; ++i)
#pragma unroll
        for (int m = 0; m < 2; ++m) acc[i][m] = (f32x4){0.f, 0.f, 0.f, 0.f};

#pragma unroll
    for (int kst = 0; kst < 3; ++kst) {
        const int kb = kst * 32 + lg * 8;
        bf16x8 a_h0 = *(const bf16x8*)&A_hi[(0  + lr) * 104 + kb];
        bf16x8 a_h1 = *(const bf16x8*)&A_hi[(16 + lr) * 104 + kb];
        bf16x8 a_l0 = *(const bf16x8*)&A_lo[(0  + lr) * 104 + kb];
        bf16x8 a_l1 = *(const bf16x8*)&A_lo[(16 + lr) * 104 + kb];
#pragma unroll
        for (int i = 0; i < 4; ++i) {
            const int oc = (wv * 4 + i) * 16 + lr;
            bf16x8 bh = *(const bf16x8*)&Bh[oc * 96 + kb];
            bf16x8 bl = *(const bf16x8*)&Bl[oc * 96 + kb];
            acc[i][0] = __builtin_amdgcn_mfma_f32_16x16x32_bf16(a_h0, bh, acc[i][0], 0, 0, 0);
            acc[i][1] = __builtin_amdgcn_mfma_f32_16x16x32_bf16(a_h1, bh, acc[i][1], 0, 0, 0);
            acc[i][0] = __builtin_amdgcn_mfma_f32_16x16x32_bf16(a_l0, bh, acc[i][0], 0, 0, 0);
            acc[i][1] = __builtin_amdgcn_mfma_f32_16x16x32_bf16(a_l1, bh, acc[i][1], 0, 0, 0);
            acc[i][0] = __builtin_amdgcn_mfma_f32_16x16x32_bf16(a_h0, bl, acc[i][0], 0, 0, 0);
            acc[i][1] = __builtin_amdgcn_mfma_f32_16x16x32_bf16(a_h1, bl, acc[i][1], 0, 0, 0);
        }
    }

    // ---- transpose D-frags -> per-thread vote column vcol[ci] (oc = t), 2 passes ----
    float vcol[32];
#pragma unroll
    for (int p = 0; p < 2; ++p) {
        __syncthreads();
        if ((wv >> 1) == p) {
#pragma unroll
            for (int i = 0; i < 4; ++i) {
                const int colbase = (wv * 4 + i) * 16 + lr - p * 128;
#pragma unroll
                for (int m = 0; m < 2; ++m)
#pragma unroll
                    for (int r = 0; r < 4; ++r)
                        vbuf[m * 16 + lg * 4 + r][colbase] = acc[i][m][r];
            }
        }
        __syncthreads();
        if ((t >> 7) == p) {
            const int cc = t & 127;
#pragma unroll
            for (int ci = 0; ci < 32; ++ci) vcol[ci] = vbuf[ci][cc];
        }
    }

    // ---- dynamic routing. Thread t owns oc=t; co=t>>3, no=t&7 ----
    const int co = t >> 3;
    const int no = t & 7;
    const float bsv = bias[t];
    float act = 0.f;
    float dlog[4] = {0.f, 0.f, 0.f, 0.f};   // cumulative distances for ci = no*4+q

    // ======== iteration 1: route is exactly uniform (logits == 0) ========
    {
        float p = 0.f;
#pragma unroll
        for (int ci = 0; ci < 32; ++ci) p += vcol[ci];
        p = bsv + p * (1.f / 32.f);
        float n2 = p * p;
        n2 += __shfl_xor(n2, 1);
        n2 += __shfl_xor(n2, 2);
        n2 += __shfl_xor(n2, 4);
        act = p * (n2 / ((1.f + n2) * sqrtf(n2 + 1e-9f)));

#pragma unroll
        for (int ci = 0; ci < 32; ++ci) {
            float pd = vcol[ci] * act;
            pd += __shfl_xor(pd, 1);
            pd += __shfl_xor(pd, 2);
            pd += __shfl_xor(pd, 4);
            if ((ci >> 2) == no) dlog[ci & 3] += pd;
        }
#pragma unroll
        for (int q = 0; q < 4; ++q) logits[no * 4 + q][co] = dlog[q];
    }
    __syncthreads();

    // ======== iterations 2..3 ========
#pragma unroll
    for (int it = 1; it < ITERS; ++it) {
        // softmax over co per ci: thread handles ci = t>>3, cols c0+8j
        {
            const int ci = t >> 3;
            const int c0 = t & 7;
            float l0 = logits[ci][c0],      l1 = logits[ci][c0 + 8];
            float l2 = logits[ci][c0 + 16], l3 = logits[ci][c0 + 24];
            float m = fmaxf(fmaxf(l0, l1), fmaxf(l2, l3));
            m = fmaxf(m, __shfl_xor(m, 1));
            m = fmaxf(m, __shfl_xor(m, 2));
            m = fmaxf(m, __shfl_xor(m, 4));
            float e0 = __expf(l0 - m), e1 = __expf(l1 - m);
            float e2 = __expf(l2 - m), e3 = __expf(l3 - m);
            float s = e0 + e1 + e2 + e3;
            s += __shfl_xor(s, 1);
            s += __shfl_xor(s, 2);
            s += __shfl_xor(s, 4);
            float inv = 1.f / s;
            route_T[c0][ci]      = e0 * inv;
            route_T[c0 + 8][ci]  = e1 * inv;
            route_T[c0 + 16][ci] = e2 * inv;
            route_T[c0 + 24][ci] = e3 * inv;
        }
        __syncthreads();

        // preact: p = bias + sum_ci route_T[co][ci] * vcol[ci]  (8 x b128 reads)
        float p = bsv;
#pragma unroll
        for (int j = 0; j < 8; ++j) {
            f32x4 rv = *(const f32x4*)&route_T[co][j * 4];
            p = fmaf(rv.x, vcol[j * 4 + 0], p);
            p = fmaf(rv.y, vcol[j * 4 + 1], p);
            p = fmaf(rv.z, vcol[j * 4 + 2], p);
            p = fmaf(rv.w, vcol[j * 4 + 3], p);
        }
        float n2 = p * p;
        n2 += __shfl_xor(n2, 1);
        n2 += __shfl_xor(n2, 2);
        n2 += __shfl_xor(n2, 4);
        act = p * (n2 / ((1.f + n2) * sqrtf(n2 + 1e-9f)));

        if (it < ITERS - 1) {
#pragma unroll
            for (int ci = 0; ci < 32; ++ci) {
                float pd = vcol[ci] * act;
                pd += __shfl_xor(pd, 1);
                pd += __shfl_xor(pd, 2);
                pd += __shfl_xor(pd, 4);
                if ((ci >> 2) == no) dlog[ci & 3] += pd;
            }
#pragma unroll
            for (int q = 0; q < 4; ++q) logits[no * 4 + q][co] = dlog[q];
            __syncthreads();
        }
    }

    // ---- out[b][co][no][h][w], oc = t ----
    out[(b * 256 + t) * (HH * WW) + h * WW + w] = act;
}

extern "C" void kernel_launch(void* const* d_in, const int* in_sizes, int n_in,
                              void* d_out, int out_size, void* d_ws, size_t ws_size,
                              hipStream_t stream) {
    const float* x    = (const float*)d_in[0];
    const float* Wt   = (const float*)d_in[1];
    const float* bias = (const float*)d_in[2];
    float* out        = (float*)d_out;
    __bf16* bp        = (__bf16*)d_ws;

    prepack_w_kernel<<<dim3(96), dim3(256), 0, stream>>>(Wt, bp);
    caps_mfma2_kernel<<<dim3(16 * HH * WW), dim3(256), 0, stream>>>(x, bp, bias, out);
}